// Round 3
// baseline (695.499 us; speedup 1.0000x reference)
//
#include <hip/hip_runtime.h>

#define HH 1024
#define SS 2048
#define BB 32

#define BM 128
#define BN 128
#define BK 64
#define NT 8                  // HH / BN
#define MT 512                // (BB*SS) / BM

typedef __attribute__((ext_vector_type(8))) __bf16 bf16x8;
typedef __attribute__((ext_vector_type(4))) float f32x4;

__device__ inline float fast_tanh(float x) {
  x = fminf(fmaxf(x, -15.f), 15.f);
  float e = __expf(2.f * x);
  return (e - 1.f) / (e + 1.f);
}

// ---------------- Kernel A: qp[b][g] = query[b]·Wa_w[g] + Wa_b[g] + Ua_b[g] --
__global__ __launch_bounds__(256) void qproj_kernel(
    const float* __restrict__ query, const float* __restrict__ Wa_w,
    const float* __restrict__ Wa_b, const float* __restrict__ Ua_b,
    float* __restrict__ qp)
{
  int wid  = (blockIdx.x * 256 + threadIdx.x) >> 6;   // 0..32767
  int lane = threadIdx.x & 63;
  int b = wid >> 10;
  int g = wid & 1023;
  const float* qrow = query + b * HH;
  const float* wrow = Wa_w + (size_t)g * HH;
  float s = 0.f;
#pragma unroll
  for (int i = 0; i < 16; ++i) {
    int k = lane + i * 64;
    s += qrow[k] * wrow[k];
  }
#pragma unroll
  for (int m = 32; m >= 1; m >>= 1) s += __shfl_xor(s, m);
  if (lane == 0) qp[b * HH + g] = s + Wa_b[g] + Ua_b[g];
}

// ---------------- Kernel B: fused k_proj GEMM + tanh + Va reduce ------------
// partials[mi][ni][128]: partial score sums over this n-tile's 128 g-columns.
__global__ __launch_bounds__(256) void score_gemm_kernel(
    const float* __restrict__ keys, const float* __restrict__ Ua_w,
    const float* __restrict__ qp, const float* __restrict__ Va_w,
    float* __restrict__ partials)
{
  __shared__ __align__(16) __bf16 At[BM * BK];
  __shared__ __align__(16) __bf16 Bt[BN * BK];
  __shared__ float psum[BM];

  // XCD-grouped mapping: the 8 n-tiles of one m-tile are 8 consecutive
  // dispatch slots on one XCD (assuming round-robin bid%8 -> XCD).
  int bid = blockIdx.x;
  int c  = bid & 7;
  int t2 = bid >> 3;
  int ni = t2 & 7;
  int mi = c + (t2 >> 3) * 8;        // 0..511

  int tid  = threadIdx.x;
  int lane = tid & 63;
  int wid  = tid >> 6;               // 0..3
  int wm = wid >> 1, wn = wid & 1;   // 2x2 wave grid, wave tile 64x64

  f32x4 acc[4][4];
#pragma unroll
  for (int i = 0; i < 4; ++i)
#pragma unroll
    for (int j = 0; j < 4; ++j) acc[i][j] = (f32x4)0.f;

  int sr = tid >> 3;                 // staging row base 0..31
  int sq = tid & 7;                  // granule 0..7 (8 bf16 = 16B)
  const float* gA = keys + (size_t)(mi * BM) * HH;
  const float* gB = Ua_w + (size_t)(ni * BN) * HH;

  for (int kt = 0; kt < HH / BK; ++kt) {
    int k0 = kt * BK;
    __syncthreads();
    // stage A (keys) fp32 -> bf16, XOR-swizzled granules
#pragma unroll
    for (int p = 0; p < 4; ++p) {
      int r = sr + p * 32;
      const float* src = gA + (size_t)r * HH + k0 + sq * 8;
      f32x4 f0 = *(const f32x4*)src;
      f32x4 f1 = *(const f32x4*)(src + 4);
      bf16x8 v;
      v[0] = (__bf16)f0[0]; v[1] = (__bf16)f0[1];
      v[2] = (__bf16)f0[2]; v[3] = (__bf16)f0[3];
      v[4] = (__bf16)f1[0]; v[5] = (__bf16)f1[1];
      v[6] = (__bf16)f1[2]; v[7] = (__bf16)f1[3];
      *(bf16x8*)&At[r * BK + ((sq ^ (r & 7)) << 3)] = v;
    }
    // stage B (Ua_w rows = g columns)
#pragma unroll
    for (int p = 0; p < 4; ++p) {
      int r = sr + p * 32;
      const float* src = gB + (size_t)r * HH + k0 + sq * 8;
      f32x4 f0 = *(const f32x4*)src;
      f32x4 f1 = *(const f32x4*)(src + 4);
      bf16x8 v;
      v[0] = (__bf16)f0[0]; v[1] = (__bf16)f0[1];
      v[2] = (__bf16)f0[2]; v[3] = (__bf16)f0[3];
      v[4] = (__bf16)f1[0]; v[5] = (__bf16)f1[1];
      v[6] = (__bf16)f1[2]; v[7] = (__bf16)f1[3];
      *(bf16x8*)&Bt[r * BK + ((sq ^ (r & 7)) << 3)] = v;
    }
    __syncthreads();
    // compute: 2 k-steps x 16 MFMA
#pragma unroll
    for (int ks = 0; ks < 2; ++ks) {
      bf16x8 af[4], bfr[4];
#pragma unroll
      for (int i = 0; i < 4; ++i) {
        int row = wm * 64 + i * 16 + (lane & 15);
        int q = ks * 4 + (lane >> 4);
        af[i] = *(const bf16x8*)&At[row * BK + ((q ^ (row & 7)) << 3)];
      }
#pragma unroll
      for (int j = 0; j < 4; ++j) {
        int row = wn * 64 + j * 16 + (lane & 15);
        int q = ks * 4 + (lane >> 4);
        bfr[j] = *(const bf16x8*)&Bt[row * BK + ((q ^ (row & 7)) << 3)];
      }
#pragma unroll
      for (int i = 0; i < 4; ++i)
#pragma unroll
        for (int j = 0; j < 4; ++j)
          acc[i][j] = __builtin_amdgcn_mfma_f32_16x16x32_bf16(
              af[i], bfr[j], acc[i][j], 0, 0, 0);
    }
  }

  // ---- epilogue: score partial = sum_g tanh(kp + qp[g]) * Va[g] ----
  if (tid < BM) psum[tid] = 0.f;
  __syncthreads();

  int b = (mi * BM) >> 11;          // batch (BM divides S)
  const float* qpb = qp + b * HH;
  int colbase = ni * BN + wn * 64 + (lane & 15);
  float vaf[4], qpf[4];
#pragma unroll
  for (int j = 0; j < 4; ++j) {
    int g = colbase + j * 16;
    vaf[j] = Va_w[g];
    qpf[j] = qpb[g];
  }
#pragma unroll
  for (int i = 0; i < 4; ++i) {
#pragma unroll
    for (int jj = 0; jj < 4; ++jj) {      // jj = row-in-frag quarter
      float v = 0.f;
#pragma unroll
      for (int j = 0; j < 4; ++j)
        v += fast_tanh(acc[i][j][jj] + qpf[j]) * vaf[j];
      // reduce across 16 columns (lanes sharing lane>>4)
      v += __shfl_xor(v, 1); v += __shfl_xor(v, 2);
      v += __shfl_xor(v, 4); v += __shfl_xor(v, 8);
      if ((lane & 15) == 0) {
        int row = wm * 64 + i * 16 + (lane >> 4) * 4 + jj;
        atomicAdd(&psum[row], v);
      }
    }
  }
  __syncthreads();
  if (tid < BM)
    partials[((size_t)mi * NT + ni) * BM + tid] = psum[tid];
}

// ---------------- Kernel C: mask + softmax, writes weights to d_out ---------
__global__ __launch_bounds__(256) void softmax_kernel(
    const float* __restrict__ partials, const int* __restrict__ mask,
    const float* __restrict__ Va_b, float* __restrict__ out)
{
  __shared__ float red[8];
  int b = blockIdx.x;
  int t = threadIdx.x;
  float vb = Va_b[0];
  float sv[8];
#pragma unroll
  for (int i = 0; i < 8; ++i) {
    int s = t + i * 256;
    int mt = b * 16 + (s >> 7);
    int ri = s & 127;
    float sc = vb;
#pragma unroll
    for (int n = 0; n < 8; ++n)
      sc += partials[((size_t)mt * NT + n) * BM + ri];
    if (mask[b * SS + s] == 0) sc = -3.402823466e+38f;
    sv[i] = sc;
  }
  float m = sv[0];
#pragma unroll
  for (int i = 1; i < 8; ++i) m = fmaxf(m, sv[i]);
#pragma unroll
  for (int x = 32; x >= 1; x >>= 1) m = fmaxf(m, __shfl_xor(m, x));
  if ((t & 63) == 0) red[t >> 6] = m;
  __syncthreads();
  m = fmaxf(fmaxf(red[0], red[1]), fmaxf(red[2], red[3]));

  float e[8];
  float sum = 0.f;
#pragma unroll
  for (int i = 0; i < 8; ++i) { e[i] = expf(sv[i] - m); sum += e[i]; }
#pragma unroll
  for (int x = 32; x >= 1; x >>= 1) sum += __shfl_xor(sum, x);
  if ((t & 63) == 0) red[4 + (t >> 6)] = sum;
  __syncthreads();
  sum = red[4] + red[5] + red[6] + red[7];
  float inv = 1.0f / sum;
#pragma unroll
  for (int i = 0; i < 8; ++i)
    out[(size_t)BB * HH + (size_t)b * SS + t + i * 256] = e[i] * inv;
}

// ---------------- Kernel D: context[b][h] = sum_s w[b][s]*keys[b][s][h] -----
__global__ __launch_bounds__(256) void context_kernel(
    const float* __restrict__ keys, const float* __restrict__ out_w,
    float* __restrict__ ctx)
{
  int b = blockIdx.x;
  int chunk = blockIdx.y;            // 16 chunks of 128 s
  int t = threadIdx.x;
  const float* w  = out_w + BB * HH + (size_t)b * SS + chunk * 128;
  const float* kp = keys + ((size_t)b * SS + chunk * 128) * HH + t * 4;
  f32x4 acc = (f32x4)0.f;
#pragma unroll 4
  for (int s = 0; s < 128; ++s) {
    float ws = w[s];
    f32x4 k4 = *(const f32x4*)(kp + (size_t)s * HH);
    acc[0] = fmaf(ws, k4[0], acc[0]);
    acc[1] = fmaf(ws, k4[1], acc[1]);
    acc[2] = fmaf(ws, k4[2], acc[2]);
    acc[3] = fmaf(ws, k4[3], acc[3]);
  }
  float* dst = ctx + (size_t)b * HH + t * 4;
  atomicAdd(dst + 0, acc[0]);
  atomicAdd(dst + 1, acc[1]);
  atomicAdd(dst + 2, acc[2]);
  atomicAdd(dst + 3, acc[3]);
}

extern "C" void kernel_launch(void* const* d_in, const int* in_sizes, int n_in,
                              void* d_out, int out_size, void* d_ws, size_t ws_size,
                              hipStream_t stream) {
  const float* query = (const float*)d_in[0];
  const float* keys  = (const float*)d_in[1];
  const int*   mask  = (const int*)d_in[2];
  const float* Wa_w  = (const float*)d_in[3];
  const float* Wa_b  = (const float*)d_in[4];
  const float* Ua_w  = (const float*)d_in[5];
  const float* Ua_b  = (const float*)d_in[6];
  const float* Va_w  = (const float*)d_in[7];
  const float* Va_b  = (const float*)d_in[8];
  float* out = (float*)d_out;

  float* qp       = (float*)d_ws;          // 32768 f32
  float* partials = qp + BB * HH;          // 512*8*128 f32 = 2 MB

  // zero the context region (filled by atomics in kernel D)
  hipMemsetAsync(d_out, 0, (size_t)BB * HH * sizeof(float), stream);

  qproj_kernel<<<8192, 256, 0, stream>>>(query, Wa_w, Wa_b, Ua_b, qp);
  score_gemm_kernel<<<MT * NT, 256, 0, stream>>>(keys, Ua_w, qp, Va_w, partials);
  softmax_kernel<<<BB, 256, 0, stream>>>(partials, mask, Va_b, out);
  context_kernel<<<dim3(BB, 16), 256, 0, stream>>>(keys, out, out);
}